// Round 7
// baseline (117.820 us; speedup 1.0000x reference)
//
#include <hip/hip_runtime.h>
#include <math.h>

// Problem constants (from reference): B=2, L=1024, D=256, P=32
#define B_ 2
#define L_ 1024
#define D_ 256
#define P_ 32
#define NROW (B_*L_)          // 2048 flattened (b,l) rows
#define C_ 16                 // L chunks for the scan
#define CL_ (L_/C_)           // 64 positions per chunk
#define PIF 3.14159265358979323846f

// ---------------------------------------------------------------------------
// Projection kernel, 768 blocks x 256 threads.
//  blocks [0, 512): values GEMM, 4 rows/block, K-SPLIT: quarter-wave q owns
//    k in [64q, 64q+64) so the block streams Wv exactly ONCE (was 4x),
//    partial accs reduced through 16 KB LDS. Wv float4 loads coalesced 1KB/wave.
//  blocks [512, 768): phase GEMM, 8 rows x 32 p; tanh -> phases,
//    sincos -> phasors (d_out) + transposed copy phasorT[(b*P+p)*L+l] (ws)
//    for coalesced access in partial/scan.
// phasorMode: 0 = float2 (cos,sin), 1 = cos only, 2 = skip. hasPT: write pcT.
// ---------------------------------------------------------------------------
__global__ __launch_bounds__(256) void k_proj3(
    const float* __restrict__ x, const float* __restrict__ Wp,
    const float* __restrict__ bp, const float* __restrict__ Wv,
    const float* __restrict__ bv, float* __restrict__ values,
    float* __restrict__ phases_out, float* __restrict__ phasor_out,
    float2* __restrict__ phasorT, int phasorMode, int hasPT)
{
    __shared__ float smem[5120];                 // 20 KB carved below
    const int tid = threadIdx.x;

    if (blockIdx.x < NROW / 4) {
        // ---- values: rows [row0, row0+4), K-split ----
        const int row0 = blockIdx.x * 4;
        float*  xsv = smem;                      // 1024 floats (4 KB)
        float4* red = (float4*)(smem + 1024);    // 1024 float4 (16 KB)

        ((float4*)xsv)[tid] = ((const float4*)(x + (size_t)row0 * D_))[tid];
        __syncthreads();

        const int q  = tid >> 6;                 // k-quarter, wave-uniform
        const int c4 = tid & 63;                 // float4 column group
        const float4* Wv4 = (const float4*)Wv;
        float4 acc[4];
        #pragma unroll
        for (int r = 0; r < 4; ++r) acc[r] = make_float4(0.f, 0.f, 0.f, 0.f);

        const int k0 = q * 64;
        #pragma unroll 4
        for (int kk = 0; kk < 64; ++kk) {
            const int k = k0 + kk;
            float4 w = Wv4[k * 64 + c4];         // coalesced 1KB/wave, Wv once/block
            #pragma unroll
            for (int r = 0; r < 4; ++r) {
                float xv = xsv[r * D_ + k];      // wave-uniform LDS broadcast
                acc[r].x += xv * w.x; acc[r].y += xv * w.y;
                acc[r].z += xv * w.z; acc[r].w += xv * w.w;
            }
        }
        #pragma unroll
        for (int r = 0; r < 4; ++r) red[(r * 4 + q) * 64 + c4] = acc[r];
        __syncthreads();

        const int r2 = tid >> 6;                 // row this thread finalizes
        float4 s0 = red[(r2 * 4 + 0) * 64 + c4];
        float4 s1 = red[(r2 * 4 + 1) * 64 + c4];
        float4 s2 = red[(r2 * 4 + 2) * 64 + c4];
        float4 s3 = red[(r2 * 4 + 3) * 64 + c4];
        const float4 b4 = ((const float4*)bv)[c4];
        float4 out;
        out.x = s0.x + s1.x + s2.x + s3.x + b4.x;
        out.y = s0.y + s1.y + s2.y + s3.y + b4.y;
        out.z = s0.z + s1.z + s2.z + s3.z + b4.z;
        out.w = s0.w + s1.w + s2.w + s3.w + b4.w;
        ((float4*)values)[(size_t)(row0 + r2) * 64 + c4] = out;
    } else {
        // ---- phases/phasors: rows [row0, row0+8) ----
        const int row0 = (blockIdx.x - NROW / 4) * 8;
        float* xs = smem;                        // 2048 floats (8 KB)
        const float4* xg4 = (const float4*)(x + (size_t)row0 * D_);
        ((float4*)xs)[tid]       = xg4[tid];
        ((float4*)xs)[tid + 256] = xg4[tid + 256];
        __syncthreads();

        const int p  = tid & (P_ - 1);
        const int rr = tid >> 5;                 // 0..7
        const float* xr = xs + rr * D_;
        float a = 0.f;
        #pragma unroll 8
        for (int k = 0; k < D_; ++k)
            a += xr[k] * Wp[k * P_ + p];         // 128B bcast per wave
        float ph = tanhf(a + bp[p]) * PIF;
        const int row = row0 + rr;
        const int idx = row * P_ + p;
        phases_out[idx] = ph;
        float s, c;
        sincosf(ph, &s, &c);
        if (phasorMode == 0) {
            ((float2*)phasor_out)[idx] = make_float2(c, s);
        } else if (phasorMode == 1) {
            phasor_out[idx] = c;
        }
        if (hasPT) {
            const int b = row >> 10, l = row & (L_ - 1);
            phasorT[(b * P_ + p) * L_ + l] = make_float2(c, s);
        }
    }
}

// ---------------------------------------------------------------------------
// Chunk partials S[b,p,c,:] = sum_{l in chunk} phasor * v.
// Phasors: coalesced 512B load from phasorT (hasPT) else strided+sincos.
// ---------------------------------------------------------------------------
__global__ __launch_bounds__(128) void k_partial(
    const float* __restrict__ values, const float* __restrict__ phases,
    const float2* __restrict__ phasorT, float4* __restrict__ S4, int hasPT)
{
    const int blk = blockIdx.x;                  // b*P_*C_ + p*C_ + c
    const int c = blk & (C_ - 1);
    const int p = (blk >> 4) & (P_ - 1);
    const int b = blk >> 9;
    const int tid = threadIdx.x;                 // 0..127
    const int l0 = c * CL_;

    __shared__ float2 pc[CL_];
    if (tid < CL_) {
        if (hasPT) {
            pc[tid] = phasorT[(b * P_ + p) * L_ + l0 + tid];
        } else {
            float ph = phases[(b * L_ + l0 + tid) * P_ + p];
            pc[tid] = make_float2(__cosf(ph), __sinf(ph));
        }
    }
    __syncthreads();

    const float2* v2 = (const float2*)(values + (size_t)(b * L_ + l0) * D_);
    float4 acc = make_float4(0.f, 0.f, 0.f, 0.f);
    #pragma unroll 8
    for (int i = 0; i < CL_; ++i) {
        float2 ph = pc[i];                       // same-addr LDS broadcast
        float2 v  = v2[i * (D_/2) + tid];        // coalesced 8B/lane (L2)
        acc.x += ph.x * v.x;
        acc.y += ph.y * v.x;
        acc.z += ph.x * v.y;
        acc.w += ph.y * v.y;
    }
    S4[((b * P_ + p) * C_ + c) * (D_/2) + tid] = acc;
}

// ---------------------------------------------------------------------------
// Scan: carry = sum of preceding chunk partials, then 64-step running sum.
// mode 0: float4 interleaved complex store; mode 1: float2 real-part store.
// PLAIN stores this round (A/B vs round-6 NT): fills sustain 5.7 TB/s with
// plain stores; testing the theory that NT throttles the write stream.
// ---------------------------------------------------------------------------
__global__ __launch_bounds__(128) void k_scan(
    const float* __restrict__ values, const float* __restrict__ phases,
    const float2* __restrict__ phasorT, const float4* __restrict__ S4,
    float* __restrict__ mem, int mode, int hasPT)
{
    const int blk = blockIdx.x;
    const int c = blk & (C_ - 1);
    const int p = (blk >> 4) & (P_ - 1);
    const int b = blk >> 9;
    const int tid = threadIdx.x;
    const int l0 = c * CL_;

    __shared__ float2 pc[CL_];
    if (tid < CL_) {
        if (hasPT) {
            pc[tid] = phasorT[(b * P_ + p) * L_ + l0 + tid];
        } else {
            float ph = phases[(b * L_ + l0 + tid) * P_ + p];
            pc[tid] = make_float2(__cosf(ph), __sinf(ph));
        }
    }

    float4 carry = make_float4(0.f, 0.f, 0.f, 0.f);
    const float4* Sbase = S4 + (size_t)(b * P_ + p) * C_ * (D_/2) + tid;
    for (int cc = 0; cc < c; ++cc) {             // ≤15 independent loads
        float4 s = Sbase[cc * (D_/2)];
        carry.x += s.x; carry.y += s.y; carry.z += s.z; carry.w += s.w;
    }
    __syncthreads();

    const float2* v2 = (const float2*)(values + (size_t)(b * L_ + l0) * D_);
    #pragma unroll 8
    for (int i = 0; i < CL_; ++i) {
        float2 ph = pc[i];
        float2 v  = v2[i * (D_/2) + tid];
        carry.x += ph.x * v.x;
        carry.y += ph.y * v.x;
        carry.z += ph.x * v.y;
        carry.w += ph.y * v.y;
        const size_t rowIdx = (size_t)(b * L_ + l0 + i) * P_ + p;
        if (mode == 0) {
            ((float4*)mem)[rowIdx * (D_/2) + tid] = carry;
        } else {
            ((float2*)mem)[rowIdx * (D_/2) + tid] = make_float2(carry.x, carry.z);
        }
    }
}

// ---------------------------------------------------------------------------
// Path B parachute (small ws): carry recomputed from values/phases via L2.
// ---------------------------------------------------------------------------
__global__ __launch_bounds__(128) void k_scan_rc(
    const float* __restrict__ values, const float* __restrict__ phases,
    float* __restrict__ mem, int mode)
{
    const int blk = blockIdx.x;
    const int c = blk & (C_ - 1);
    const int p = (blk >> 4) & (P_ - 1);
    const int b = blk >> 9;
    const int tid = threadIdx.x;
    const int l0 = c * CL_;

    const float2* vb = (const float2*)(values + (size_t)b * L_ * D_);
    float4 carry = make_float4(0.f, 0.f, 0.f, 0.f);
    for (int l = 0; l < l0; ++l) {
        float ph = phases[(b * L_ + l) * P_ + p];
        float s = __sinf(ph), cs = __cosf(ph);
        float2 v = vb[l * (D_/2) + tid];
        carry.x += cs * v.x; carry.y += s * v.x;
        carry.z += cs * v.y; carry.w += s * v.y;
    }
    for (int i = 0; i < CL_; ++i) {
        const int l = l0 + i;
        float ph = phases[(b * L_ + l) * P_ + p];
        float s = __sinf(ph), cs = __cosf(ph);
        float2 v = vb[l * (D_/2) + tid];
        carry.x += cs * v.x; carry.y += s * v.x;
        carry.z += cs * v.y; carry.w += s * v.y;
        const size_t rowIdx = (size_t)(b * L_ + l) * P_ + p;
        if (mode == 0) ((float4*)mem)[rowIdx * (D_/2) + tid] = carry;
        else ((float2*)mem)[rowIdx * (D_/2) + tid] = make_float2(carry.x, carry.z);
    }
}

extern "C" void kernel_launch(void* const* d_in, const int* in_sizes, int n_in,
                              void* d_out, int out_size, void* d_ws, size_t ws_size,
                              hipStream_t stream) {
    const float* x  = (const float*)d_in[0];
    const float* Wp = (const float*)d_in[1];
    const float* bp = (const float*)d_in[2];
    const float* Wv = (const float*)d_in[3];
    const float* bv = (const float*)d_in[4];
    float* out = (float*)d_out;

    const size_t nMemF = (size_t)2 * B_ * L_ * P_ * D_;  // 33554432 (interleaved)
    const size_t nMemR = (size_t)B_ * L_ * P_ * D_;      // 16777216 (real only)
    const size_t nPh   = (size_t)B_ * L_ * P_;           // 65536

    // Output layout mode by out_size (round-3/5 verified: mode 0 —
    // memory interleaved complex | phases | phasors interleaved).
    int mode; size_t memFloats;
    if ((size_t)out_size >= nMemF + 3 * nPh) { mode = 0; memFloats = nMemF; }
    else                                     { mode = 1; memFloats = nMemR; }
    const bool memFits      = (size_t)out_size >= memFloats;
    const bool phasesInOut  = (size_t)out_size >= memFloats + nPh;
    const bool phasorsInOut =
        (size_t)out_size >= memFloats + nPh + (mode == 0 ? 2 * nPh : nPh);

    // ws layout: values | phasesWs | S4 | phasorT
    const size_t valB = (size_t)B_ * L_ * D_ * sizeof(float);                // 2 MB
    const size_t phB  = nPh * sizeof(float);                                 // 256 KB
    const size_t s4B  = (size_t)B_ * P_ * C_ * (D_/2) * sizeof(float4);      // 2 MB
    const size_t ptB  = (size_t)B_ * P_ * L_ * sizeof(float2);               // 512 KB
    float*  values   = (float*)d_ws;
    float*  phasesWs = (float*)((char*)d_ws + valB);
    float4* S4       = (float4*)((char*)d_ws + valB + phB);
    float2* phasorT  = (float2*)((char*)d_ws + valB + phB + s4B);

    float* phasesPtr = phasesInOut ? (out + memFloats)
                     : (ws_size >= valB + phB ? phasesWs : nullptr);
    if (phasesPtr == nullptr) return;            // unreachable (ws verified big enough)

    float* phasorPtr = phasorsInOut ? (out + memFloats + nPh) : nullptr;
    const int phasorMode = phasorsInOut ? mode : 2;

    const bool pathA = ws_size >= valB + phB + s4B;          // partials fit
    const int  hasPT = (pathA && ws_size >= valB + phB + s4B + ptB) ? 1 : 0;

    k_proj3<<<NROW / 4 + NROW / 8, 256, 0, stream>>>(
        x, Wp, bp, Wv, bv, values, phasesPtr, phasorPtr, phasorT,
        phasorMode, hasPT);
    if (!memFits) return;

    if (pathA) {
        k_partial<<<B_ * P_ * C_, 128, 0, stream>>>(values, phasesPtr, phasorT,
                                                    S4, hasPT);
        k_scan<<<B_ * P_ * C_, 128, 0, stream>>>(values, phasesPtr, phasorT,
                                                 S4, out, mode, hasPT);
    } else {
        k_scan_rc<<<B_ * P_ * C_, 128, 0, stream>>>(values, phasesPtr, out, mode);
    }
}